// Round 17
// baseline (176.644 us; speedup 1.0000x reference)
//
#include <hip/hip_runtime.h>
#include <math.h>

#define B_   16
#define D_   256
#define T_   4096
#define NQn  8
#define K_   1024
#define DC_  128
#define M_   65536

typedef short bf16x8 __attribute__((ext_vector_type(8)));
typedef float f32x4  __attribute__((ext_vector_type(4)));

static __device__ __forceinline__ unsigned short f2bf(float f) {
    unsigned u = __float_as_uint(f);
    unsigned r = (u + 0x7fffu + ((u >> 16) & 1u)) >> 16;
    return (unsigned short)r;
}

// packed f32x2 -> bf16x2 (RNE), 1 instruction
static __device__ __forceinline__ int pk2(float lo, float hi) {
    int r;
    asm("v_cvt_pk_bf16_f32 %0, %1, %2" : "=v"(r) : "v"(lo), "v"(hi));
    return r;
}
// (x - t) elementwise on packed bf16x2
static __device__ __forceinline__ int sub2(int x, int t) {
    float xl = __uint_as_float(((unsigned)x) << 16);
    float xh = __uint_as_float(((unsigned)x) & 0xFFFF0000u);
    float tl = __uint_as_float(((unsigned)t) << 16);
    float th = __uint_as_float(((unsigned)t) & 0xFFFF0000u);
    return pk2(xl - tl, xh - th);
}

static __device__ __forceinline__ f32x4 MFMA(bf16x8 a, bf16x8 b, f32x4 c) {
    return __builtin_amdgcn_mfma_f32_16x16x32_bf16(a, b, c, 0, 0, 0);
}

#define EXP2(x) __builtin_amdgcn_exp2f(x)
#define LOG2(x) __builtin_amdgcn_logf(x)

__global__ void final_k(const float* __restrict__ acc, float* __restrict__ out) {
    out[0] = acc[0] * (1.f / 262144.f);   // / (4 * B * T)
}

// ---------------------------------------------------------------- fused prologue
// blocks 0..320  : stream reformat (per-q 320KB: [Win_perm 4 chunks][emb_perm 16],
//                  chunk=16KB wave read-order; emb scaled 1/(64*ln2)); block 320
//                  also writes b_in into gbias[4096..4607] and zeroes accp.
// blocks 321..576: g[k] = |e_k|^2/(128*ln2); tab[k][d] = embed[k]·Wout[d]+b_out[d]
__global__ __launch_bounds__(256) void prep_all_k(
    const float* __restrict__ Win, const float* __restrict__ bin,
    const float* __restrict__ emb,
    const float* __restrict__ Wout, const float* __restrict__ bout,
    unsigned short* __restrict__ stream, unsigned short* __restrict__ tab,
    float* __restrict__ gbias, float* __restrict__ accp)
{
    const int bid = blockIdx.x;
    const int tid = threadIdx.x;
    if (bid < 321) {
        if (bid == 320) {
            gbias[4096 + tid]       = bin[tid];
            gbias[4096 + 256 + tid] = bin[256 + tid];
            if (tid == 0) accp[0] = 0.f;
            return;
        }
        int u = bid * 256 + tid;              // 16B unit, 0..81919
        int idx = u >> 10;                    // chunk 0..79
        int q = idx / 20, r = idx - q * 20;
        int w = u & 1023;
        int lane = w & 63, blk = w >> 6;
        int l15 = lane & 15, lg4 = lane >> 4;
        unsigned short o[8];
        if (r < 4) {
            int c  = 32 * r + 16 * (blk >> 3) + l15;
            int d0 = 32 * (blk & 7) + 8 * lg4;
            const float* s = Win + ((size_t)q * DC_ + c) * D_ + d0;
            #pragma unroll
            for (int j = 0; j < 8; ++j) o[j] = f2bf(s[j]);
        } else {
            int ch = r - 4;
            int code = (ch * 4 + (blk >> 2)) * 16 + l15;
            int s4 = blk & 3;
            const float* s = emb + ((size_t)q * K_ + code) * DC_ + 32 * s4 + 4 * lg4;
            const float ESC = 1.44269504089f / 64.0f;
            #pragma unroll
            for (int j = 0; j < 8; ++j)
                o[j] = f2bf(s[16 * (j >> 2) + (j & 3)] * ESC);
        }
        *(int4*)&stream[(size_t)u * 8] = *(int4*)o;
        return;
    }
    // ---- tab + g ----
    __shared__ float E[16][128];
    const int pb = bid - 321;
    const int iq = pb >> 6;
    const int k0 = (pb & 63) << 4;
    {
        const float* src = emb + ((size_t)iq * K_ + k0) * DC_;
        #pragma unroll
        for (int it = 0; it < 2; ++it) {
            int lin = it * 1024 + tid * 4;
            float4 v = *(const float4*)(src + lin);
            *(float4*)&E[lin >> 7][lin & 127] = v;
        }
    }
    __syncthreads();
    if (tid < 16) {
        float e2 = 0.f;
        for (int c2 = 0; c2 < 128; ++c2) { float e = E[tid][c2]; e2 += e * e; }
        gbias[iq * K_ + k0 + tid] = e2 * (1.44269504089f / 128.f);
    }
    if (iq < 3) {
        const int d = tid;
        float acc[16];
        #pragma unroll
        for (int kk = 0; kk < 16; ++kk) acc[kk] = 0.f;
        const float* wp = Wout + ((size_t)iq * D_ + d) * DC_;
        for (int c2 = 0; c2 < 128; ++c2) {
            float w = wp[c2];
            #pragma unroll
            for (int kk = 0; kk < 16; ++kk) acc[kk] = fmaf(E[kk][c2], w, acc[kk]);
        }
        float bo = bout[iq * D_ + d];
        unsigned short* tq = tab + ((size_t)iq << 18);
        #pragma unroll
        for (int kk = 0; kk < 16; ++kk)
            tq[((size_t)(k0 + kk) << 8) + d] = f2bf(acc[kk] + bo);
    }
}

// ---------------------------------------------------------------- fused RVQ
// rf=1: 1024 blocks x 256 threads (4 waves x 16 rows). 2-slot ring (2x16KB) +
// gb 18K + tgt 1K = 51K LDS -> 3 blocks/CU = 3 waves/SIMD.
#define GLDS(SRC, DST) __builtin_amdgcn_global_load_lds( \
    (const __attribute__((address_space(1))) unsigned int*)(SRC), \
    (__attribute__((address_space(3))) unsigned int*)(DST), 16, 0, 0)

// ring: 2 x 16KB slots at LDSM+0..32K. gb at 32768 (18KB). tgt at 51200 (1KB).
// Per-chunk: read slot cslot (chunk c, staged last period, drained by vmcnt(0));
// after barrier stage chunk c+1 into slot cslot^1 (chunk c-1's slot; all waves
// are past reading it thanks to the barrier).
#define ITERTOP(BUFP) do { \
    BUFP = LDSM + (cslot << 14); \
    asm volatile("s_waitcnt vmcnt(0)" ::: "memory"); \
    __builtin_amdgcn_s_barrier(); \
    const char* sc_ = sp + (wv << 12) + (lane << 4); \
    char* dc_ = LDSM + ((cslot ^ 1) << 14) + (wv << 12); \
    GLDS(sc_, dc_); GLDS(sc_ + 1024, dc_ + 1024); \
    GLDS(sc_ + 2048, dc_ + 2048); GLDS(sc_ + 3072, dc_ + 3072); \
    sp += 16384; if (sp == send) sp = sbase; \
    cslot ^= 1; \
    __builtin_amdgcn_sched_barrier(0); \
} while (0)

static __device__ __forceinline__ void mfma_chunk(
    const char* bufp, int lane, const bf16x8 (&xpf)[4], f32x4 (&acc)[4])
{
    #pragma unroll
    for (int cf = 0; cf < 4; ++cf) {
        f32x4 a0 = {0.f, 0.f, 0.f, 0.f};
        #pragma unroll
        for (int ss = 0; ss < 4; ++ss) {
            bf16x8 a = *(const bf16x8*)(bufp + (((cf * 4 + ss) * 64 + lane) << 4));
            a0 = MFMA(a, xpf[ss], a0);
        }
        acc[cf] = a0;
    }
}

// EPI: exp2 + packed-index argmax. Packed layout low 8 bits: [7:6]=i, [5:0]=cfg.
template<bool LEAN>
static __device__ __forceinline__ void epi8(
    const f32x4 (&acc)[4], int ch, const float* gq, int lg4,
    float& lsum, float& bv)
{
    #pragma unroll
    for (int cf = 0; cf < 4; ++cf) {
        int cfg = ch * 4 + cf;
        float4 gv = *(const float4*)(gq + cfg * 16 + lg4 * 4);
        const f32x4& A = acc[cf];
        float e0 = EXP2(A[0] - gv.x);
        float e1 = EXP2(A[1] - gv.y);
        float e2 = EXP2(A[2] - gv.z);
        float e3 = EXP2(A[3] - gv.w);
        if (LEAN) {
            lsum += (e0 + e1) + (e2 + e3);
        } else {
            unsigned cv = (unsigned)cfg;
            float p0 = __uint_as_float((__float_as_uint(e0) & 0xFFFFFF00u) | cv);
            float p1 = __uint_as_float(((__float_as_uint(e1) & 0xFFFFFF00u) | cv) | 64u);
            float p2 = __uint_as_float(((__float_as_uint(e2) & 0xFFFFFF00u) | cv) | 128u);
            float p3 = __uint_as_float(((__float_as_uint(e3) & 0xFFFFFF00u) | cv) | 192u);
            lsum += (p0 + p1) + (p2 + p3);
            bv = fmaxf(bv, fmaxf(fmaxf(p0, p1), fmaxf(p2, p3)));
        }
    }
}

template<bool LEAN>
static __device__ __forceinline__ void q_body(
    int q, char* LDSM, const float* gb,
    const char*& sp, const char* sbase, const char* send, int& cslot,
    int wv, int lane, int l15, int lg4,
    bf16x8 (&xb)[8], const unsigned short* tab, const char* sq, float& loss)
{
    int tgt;
    {
        const int* tl = (const int*)(LDSM + 51200);
        tgt = tl[(wv * 4 + q) * 16 + l15];
    }

    // ---- GEMM1: xp = x·Win^T + b_in (4 chunks) ----
    bf16x8 xpf[4];
    #pragma unroll
    for (int S = 0; S < 4; ++S) {
        const char* bufp;
        ITERTOP(bufp);
        float4 b0 = *(const float4*)(gb + 4096 + q * 128 + 32 * S + 4 * lg4);
        float4 b1 = *(const float4*)(gb + 4096 + q * 128 + 32 * S + 16 + 4 * lg4);
        f32x4 a00 = {0.f, 0.f, 0.f, 0.f}, a10 = a00;
        #pragma unroll
        for (int ss = 0; ss < 8; ++ss) {
            bf16x8 w0 = *(const bf16x8*)(bufp + (((ss) * 64 + lane) << 4));
            bf16x8 w1 = *(const bf16x8*)(bufp + (((8 + ss) * 64 + lane) << 4));
            a00 = MFMA(w0, xb[ss], a00);
            a10 = MFMA(w1, xb[ss], a10);
        }
        int4 u0;
        u0.x = pk2(a00[0] + b0.x, a00[1] + b0.y);
        u0.y = pk2(a00[2] + b0.z, a00[3] + b0.w);
        u0.z = pk2(a10[0] + b1.x, a10[1] + b1.y);
        u0.w = pk2(a10[2] + b1.z, a10[3] + b1.w);
        xpf[S] = *(bf16x8*)&u0;
    }

    // ---- GEMM2: logits2 vs 1024 codes, A/B-pipelined epilogue ----
    const float* gq = gb + (q << 10);
    float lsum = 0.f;
    float bv   = 0.f;
    int   bi   = 0;
    f32x4 A[4], Bq[4];
    {
        const char* bufp;
        ITERTOP(bufp);
        mfma_chunk(bufp, lane, xpf, A);
    }
    #pragma unroll 1
    for (int t = 0; t < 7; ++t) {
        {
            const char* bufp;
            ITERTOP(bufp);
            mfma_chunk(bufp, lane, xpf, Bq);
            epi8<LEAN>(A, 2 * t, gq, lg4, lsum, bv);
        }
        {
            const char* bufp;
            ITERTOP(bufp);
            mfma_chunk(bufp, lane, xpf, A);
            epi8<LEAN>(Bq, 2 * t + 1, gq, lg4, lsum, bv);
        }
    }
    {
        const char* bufp;
        ITERTOP(bufp);
        mfma_chunk(bufp, lane, xpf, Bq);
        epi8<LEAN>(A, 14, gq, lg4, lsum, bv);
    }
    epi8<LEAN>(Bq, 15, gq, lg4, lsum, bv);

    // ---- pick = dot(xp_row, F[tgt_row]) - g[tgt] via MFMA diagonal ----
    float pickv;
    {
        int t = tgt;
        const char* fb = sq + ((4 + (t >> 6)) << 14)
                       + (((((t >> 4) & 3) << 8) + (lg4 << 4) + (t & 15)) << 4);
        bf16x8 f0 = *(const bf16x8*)(fb);
        bf16x8 f1 = *(const bf16x8*)(fb + 1024);
        bf16x8 f2 = *(const bf16x8*)(fb + 2048);
        bf16x8 f3 = *(const bf16x8*)(fb + 3072);
        f32x4 pa = {0.f, 0.f, 0.f, 0.f};
        pa = MFMA(f0, xpf[0], pa);
        pa = MFMA(f1, xpf[1], pa);
        pa = MFMA(f2, xpf[2], pa);
        pa = MFMA(f3, xpf[3], pa);
        int r = l15 & 3;
        float dv = (r == 0) ? pa[0] : ((r == 1) ? pa[1] : ((r == 2) ? pa[2] : pa[3]));
        float gt = gq[t];
        pickv = (lg4 == (l15 >> 2)) ? (dv - gt) : 0.f;
    }

    // ---- combine lane-groups ----
    {
        float pk10 = 0.f;
        if (!LEAN) {
            unsigned pb = __float_as_uint(bv);
            unsigned code = ((pb & 63u) << 4) | (unsigned)(lg4 << 2) | ((pb >> 6) & 3u);
            pk10 = __uint_as_float((pb & 0xFFFFFC00u) | code);
        }
        #pragma unroll
        for (int off = 16; off <= 32; off <<= 1) {
            lsum  += __shfl_xor(lsum, off);
            pickv += __shfl_xor(pickv, off);
            if (!LEAN) pk10 = fmaxf(pk10, __shfl_xor(pk10, off));
        }
        if (!LEAN) bi = (int)(__float_as_uint(pk10) & 1023u);
        if (lane < 16) loss += LOG2(lsum) - pickv;
    }

    // ---- residual update ----
    if (!LEAN) {
        const unsigned short* tq = tab + ((size_t)q << 18);
        const unsigned short* trow = tq + ((size_t)bi << 8) + (lg4 << 3);
        #pragma unroll
        for (int s = 0; s < 8; ++s) {
            int4 tv = *(const int4*)(trow + (s << 5));
            int4 xv = *(int4*)&xb[s];
            int4 ov;
            ov.x = sub2(xv.x, tv.x); ov.y = sub2(xv.y, tv.y);
            ov.z = sub2(xv.z, tv.z); ov.w = sub2(xv.w, tv.w);
            *(int4*)&xb[s] = ov;
        }
    }
}

__global__ __launch_bounds__(256, 2) void rvq_k(
    const float* __restrict__ X,              // (B,256,4096) f32
    const unsigned short* __restrict__ stream,
    const float* __restrict__ gbias,          // [g 4096][bias 512] f32
    const unsigned short* __restrict__ tab,   // (3,1024,256) bf16
    const int* __restrict__ tlc,
    float* __restrict__ accp)
{
    __shared__ __align__(16) char LDSM[52224]; // 32K ring + 18K gb + 1K tgt

    const int tid  = threadIdx.x;
    const int lane = tid & 63;
    const int wv   = tid >> 6;
    const int l15  = lane & 15;
    const int lg4  = lane >> 4;
    const int row_base = blockIdx.x * 64 + wv * 16;

    // residual fragments: 16 rows x 256 d, bf16, loaded+transposed in-register
    bf16x8 xb[8];
    {
        const int row = row_base + l15;
        const float* xpr = X + ((size_t)(row >> 12) << 20) + (row & (T_ - 1));
        #pragma unroll
        for (int s = 0; s < 8; ++s) {
            float f[8];
            #pragma unroll
            for (int j = 0; j < 8; ++j)
                f[j] = xpr[(size_t)((s << 5) + (lg4 << 3) + j) << 12];
            int4 u;
            u.x = pk2(f[0], f[1]); u.y = pk2(f[2], f[3]);
            u.z = pk2(f[4], f[5]); u.w = pk2(f[6], f[7]);
            xb[s] = *(bf16x8*)&u;
        }
    }

    // tlc prologue: lane (q=lg4, row=l15) -> LDS
    {
        int* tl = (int*)(LDSM + 51200);
        int q0 = lg4;
        int r0 = row_base + l15;
        int t0 = tlc[(size_t)(r0 >> 12) * (NQn * T_) + q0 * T_ + (r0 & (T_ - 1))];
        tl[(wv * 4 + q0) * 16 + l15] = t0;
    }
    __builtin_amdgcn_sched_barrier(0);

    // gb staging (18KB) + chunk 0 (2-slot ring: stage ONLY chunk 0 here)
    const char* sbase = (const char*)stream;
    const char* send  = sbase + 80 * 16384;
    {
        const char* gs = (const char*)gbias;
        #pragma unroll
        for (int k = 0; k < 4; ++k)
            GLDS(gs + (((k * 4 + wv) * 64 + lane) << 4),
                 LDSM + 32768 + ((k * 4 + wv) << 10));
        if (wv < 2)
            GLDS(gs + 16384 + ((wv * 64 + lane) << 4),
                 LDSM + 32768 + 16384 + (wv << 10));
    }
    {
        const char* s0 = sbase + (wv << 12) + (lane << 4);
        char* d0 = LDSM + (wv << 12);
        GLDS(s0, d0); GLDS(s0 + 1024, d0 + 1024);
        GLDS(s0 + 2048, d0 + 2048); GLDS(s0 + 3072, d0 + 3072);
    }
    const char* sp = sbase + 16384;   // next chunk to stage = chunk 1
    int cslot = 0;                    // chunk 0 lives in slot 0
    __syncthreads();   // drains vmcnt+lgkm: tgt visible, chunk 0 + gb staged

    float loss = 0.f;
    const float* gb = (const float*)(LDSM + 32768);

    #pragma unroll 1
    for (int q = 0; q < 3; ++q)
        q_body<false>(q, LDSM, gb, sp, sbase, send, cslot,
                      wv, lane, l15, lg4, xb, tab,
                      sbase + (size_t)q * 327680, loss);
    q_body<true>(3, LDSM, gb, sp, sbase, send, cslot,
                 wv, lane, l15, lg4, xb, tab,
                 sbase + (size_t)3 * 327680, loss);

    asm volatile("s_waitcnt vmcnt(0)" ::: "memory");  // drain dummy tail stages
    #pragma unroll
    for (int off = 1; off < 64; off <<= 1) loss += __shfl_xor(loss, off);
    if (lane == 0) atomicAdd(accp, loss * 0.69314718056f);
}

// ---------------------------------------------------------------- launch
extern "C" void kernel_launch(void* const* d_in, const int* in_sizes, int n_in,
                              void* d_out, int out_size, void* d_ws, size_t ws_size,
                              hipStream_t stream_)
{
    (void)in_sizes; (void)n_in; (void)out_size; (void)ws_size;
    const float* dstart = (const float*)d_in[0];
    const int*   tlc    = (const int*)d_in[1];
    const float* Win    = (const float*)d_in[2];
    const float* bin    = (const float*)d_in[3];
    const float* Wout   = (const float*)d_in[4];
    const float* bout   = (const float*)d_in[5];
    const float* emb    = (const float*)d_in[6];

    char* ws = (char*)d_ws;
    size_t off = 0;
    unsigned short* strm = (unsigned short*)(ws + off); off += (size_t)80 * 16384;       // 1.25 MB
    unsigned short* tab  = (unsigned short*)(ws + off); off += (size_t)3 * K_ * D_ * 2;  // 1.5 MB
    float*          gbias= (float*)(ws + off);          off += (size_t)4608 * 4;         // 18 KB
    float*          accp = (float*)(ws + off);          off += 256;

    prep_all_k<<<577, 256, 0, stream_>>>(Win, bin, emb, Wout, bout,
                                         strm, tab, gbias, accp);
    rvq_k<<<1024, 256, 0, stream_>>>(dstart, strm, gbias, tab, tlc, accp);
    final_k<<<1, 1, 0, stream_>>>(accp, (float*)d_out);
}

// Round 18
// 153.499 us; speedup vs baseline: 1.1508x; 1.1508x over previous
//
#include <hip/hip_runtime.h>
#include <math.h>

#define B_   16
#define D_   256
#define T_   4096
#define NQn  8
#define K_   1024
#define DC_  128
#define M_   65536

typedef short bf16x8 __attribute__((ext_vector_type(8)));
typedef float f32x4  __attribute__((ext_vector_type(4)));

static __device__ __forceinline__ unsigned short f2bf(float f) {
    unsigned u = __float_as_uint(f);
    unsigned r = (u + 0x7fffu + ((u >> 16) & 1u)) >> 16;
    return (unsigned short)r;
}

// packed f32x2 -> bf16x2 (RNE), 1 instruction
static __device__ __forceinline__ int pk2(float lo, float hi) {
    int r;
    asm("v_cvt_pk_bf16_f32 %0, %1, %2" : "=v"(r) : "v"(lo), "v"(hi));
    return r;
}
// (x - t) elementwise on packed bf16x2
static __device__ __forceinline__ int sub2(int x, int t) {
    float xl = __uint_as_float(((unsigned)x) << 16);
    float xh = __uint_as_float(((unsigned)x) & 0xFFFF0000u);
    float tl = __uint_as_float(((unsigned)t) << 16);
    float th = __uint_as_float(((unsigned)t) & 0xFFFF0000u);
    return pk2(xl - tl, xh - th);
}

static __device__ __forceinline__ f32x4 MFMA(bf16x8 a, bf16x8 b, f32x4 c) {
    return __builtin_amdgcn_mfma_f32_16x16x32_bf16(a, b, c, 0, 0, 0);
}

#define EXP2(x) __builtin_amdgcn_exp2f(x)
#define LOG2(x) __builtin_amdgcn_logf(x)

__global__ void final_k(const float* __restrict__ acc, float* __restrict__ out) {
    out[0] = acc[0] * (1.f / 262144.f);   // / (4 * B * T)
}

// ---------------------------------------------------------------- fused prologue
// blocks 0..320  : stream reformat (per-q 320KB: [Win_perm 4 chunks][emb_perm 16],
//                  chunk=16KB wave read-order; emb scaled 1/(64*ln2)); block 320
//                  also writes b_in into gbias[4096..4607] and zeroes accp.
// blocks 321..576: g[k] = |e_k|^2/(128*ln2); tab[k][d] = embed[k]·Wout[d]+b_out[d]
__global__ __launch_bounds__(256) void prep_all_k(
    const float* __restrict__ Win, const float* __restrict__ bin,
    const float* __restrict__ emb,
    const float* __restrict__ Wout, const float* __restrict__ bout,
    unsigned short* __restrict__ stream, unsigned short* __restrict__ tab,
    float* __restrict__ gbias, float* __restrict__ accp)
{
    const int bid = blockIdx.x;
    const int tid = threadIdx.x;
    if (bid < 321) {
        if (bid == 320) {
            gbias[4096 + tid]       = bin[tid];
            gbias[4096 + 256 + tid] = bin[256 + tid];
            if (tid == 0) accp[0] = 0.f;
            return;
        }
        int u = bid * 256 + tid;              // 16B unit, 0..81919
        int idx = u >> 10;                    // chunk 0..79
        int q = idx / 20, r = idx - q * 20;
        int w = u & 1023;
        int lane = w & 63, blk = w >> 6;
        int l15 = lane & 15, lg4 = lane >> 4;
        unsigned short o[8];
        if (r < 4) {
            int c  = 32 * r + 16 * (blk >> 3) + l15;
            int d0 = 32 * (blk & 7) + 8 * lg4;
            const float* s = Win + ((size_t)q * DC_ + c) * D_ + d0;
            #pragma unroll
            for (int j = 0; j < 8; ++j) o[j] = f2bf(s[j]);
        } else {
            int ch = r - 4;
            int code = (ch * 4 + (blk >> 2)) * 16 + l15;
            int s4 = blk & 3;
            const float* s = emb + ((size_t)q * K_ + code) * DC_ + 32 * s4 + 4 * lg4;
            const float ESC = 1.44269504089f / 64.0f;
            #pragma unroll
            for (int j = 0; j < 8; ++j)
                o[j] = f2bf(s[16 * (j >> 2) + (j & 3)] * ESC);
        }
        *(int4*)&stream[(size_t)u * 8] = *(int4*)o;
        return;
    }
    // ---- tab + g ----
    __shared__ float E[16][128];
    const int pb = bid - 321;
    const int iq = pb >> 6;
    const int k0 = (pb & 63) << 4;
    {
        const float* src = emb + ((size_t)iq * K_ + k0) * DC_;
        #pragma unroll
        for (int it = 0; it < 2; ++it) {
            int lin = it * 1024 + tid * 4;
            float4 v = *(const float4*)(src + lin);
            *(float4*)&E[lin >> 7][lin & 127] = v;
        }
    }
    __syncthreads();
    if (tid < 16) {
        float e2 = 0.f;
        for (int c2 = 0; c2 < 128; ++c2) { float e = E[tid][c2]; e2 += e * e; }
        gbias[iq * K_ + k0 + tid] = e2 * (1.44269504089f / 128.f);
    }
    if (iq < 3) {
        const int d = tid;
        float acc[16];
        #pragma unroll
        for (int kk = 0; kk < 16; ++kk) acc[kk] = 0.f;
        const float* wp = Wout + ((size_t)iq * D_ + d) * DC_;
        for (int c2 = 0; c2 < 128; ++c2) {
            float w = wp[c2];
            #pragma unroll
            for (int kk = 0; kk < 16; ++kk) acc[kk] = fmaf(E[kk][c2], w, acc[kk]);
        }
        float bo = bout[iq * D_ + d];
        unsigned short* tq = tab + ((size_t)iq << 18);
        #pragma unroll
        for (int kk = 0; kk < 16; ++kk)
            tq[((size_t)(k0 + kk) << 8) + d] = f2bf(acc[kk] + bo);
    }
}

// ---------------------------------------------------------------- fused RVQ
#define GLDS(SRC, DST) __builtin_amdgcn_global_load_lds( \
    (const __attribute__((address_space(1))) unsigned int*)(SRC), \
    (__attribute__((address_space(3))) unsigned int*)(DST), 16, 0, 0)

// ring: 3 x 16KB slots at LDSM+0..48K. gb at 49152 (18KB). tgt at 67584 (2KB).
#define ITERTOP(BUFP) do { \
    BUFP = LDSM + (cslot << 14); \
    asm volatile("s_waitcnt vmcnt(4)" ::: "memory"); \
    __builtin_amdgcn_s_barrier(); \
    int ss_ = (cslot == 0) ? 2 : cslot - 1; \
    const char* sc_ = sp + (wv << 12) + (lane << 4); \
    char* dc_ = LDSM + (ss_ << 14) + (wv << 12); \
    GLDS(sc_, dc_); GLDS(sc_ + 1024, dc_ + 1024); \
    GLDS(sc_ + 2048, dc_ + 2048); GLDS(sc_ + 3072, dc_ + 3072); \
    sp += 16384; if (sp == send) sp = sbase; \
    cslot = (cslot == 2) ? 0 : cslot + 1; \
    __builtin_amdgcn_sched_barrier(0); \
} while (0)

static __device__ __forceinline__ void mfma_chunk(
    const char* bufp, int lane, const bf16x8 (&xpf)[2][4], f32x4 (&acc)[8])
{
    #pragma unroll
    for (int cfp = 0; cfp < 2; ++cfp)
        #pragma unroll
        for (int cl = 0; cl < 2; ++cl) {
            f32x4 a0 = {0.f, 0.f, 0.f, 0.f}, a1 = a0;
            #pragma unroll
            for (int ss = 0; ss < 4; ++ss) {
                bf16x8 a = *(const bf16x8*)(bufp + ((((cfp * 2 + cl) * 4 + ss) * 64 + lane) << 4));
                a0 = MFMA(a, xpf[0][ss], a0);
                a1 = MFMA(a, xpf[1][ss], a1);
            }
            acc[cfp * 4 + cl * 2 + 0] = a0;
            acc[cfp * 4 + cl * 2 + 1] = a1;
        }
}

// EPI: exp2 + packed-index argmax. Packed layout low 8 bits: [7:6]=i, [5:0]=cfg.
template<bool LEAN>
static __device__ __forceinline__ void epi8(
    const f32x4 (&acc)[8], int ch, const float* gq, int lg4,
    float (&lsum)[2], float (&bv)[2])
{
    #pragma unroll
    for (int cfp = 0; cfp < 2; ++cfp)
        #pragma unroll
        for (int cl = 0; cl < 2; ++cl) {
            int cfg = ch * 4 + cfp * 2 + cl;
            float4 gv = *(const float4*)(gq + cfg * 16 + lg4 * 4);
            #pragma unroll
            for (int rf = 0; rf < 2; ++rf) {
                const f32x4& A = acc[cfp * 4 + cl * 2 + rf];
                float e0 = EXP2(A[0] - gv.x);
                float e1 = EXP2(A[1] - gv.y);
                float e2 = EXP2(A[2] - gv.z);
                float e3 = EXP2(A[3] - gv.w);
                if (LEAN) {
                    lsum[rf] += (e0 + e1) + (e2 + e3);
                } else {
                    unsigned cv = (unsigned)cfg;
                    float p0 = __uint_as_float((__float_as_uint(e0) & 0xFFFFFF00u) | cv);
                    float p1 = __uint_as_float(((__float_as_uint(e1) & 0xFFFFFF00u) | cv) | 64u);
                    float p2 = __uint_as_float(((__float_as_uint(e2) & 0xFFFFFF00u) | cv) | 128u);
                    float p3 = __uint_as_float(((__float_as_uint(e3) & 0xFFFFFF00u) | cv) | 192u);
                    lsum[rf] += (p0 + p1) + (p2 + p3);
                    bv[rf] = fmaxf(bv[rf], fmaxf(fmaxf(p0, p1), fmaxf(p2, p3)));
                }
            }
        }
}

template<bool LEAN>
static __device__ __forceinline__ void q_body(
    int q, char* LDSM, const float* gb,
    const char*& sp, const char* sbase, const char* send, int& cslot,
    int wv, int lane, int l15, int lg4,
    bf16x8 (&xb)[2][8], const unsigned short* tab, const char* sq, float& loss)
{
    int tgt[2];
    {
        const int* tl = (const int*)(LDSM + 67584);
        tgt[0] = tl[(wv * 4 + q) * 32 + l15];
        tgt[1] = tl[(wv * 4 + q) * 32 + 16 + l15];
    }

    // ---- GEMM1: xp = x·Win^T + b_in (4 chunks) ----
    bf16x8 xpf[2][4];
    #pragma unroll
    for (int S = 0; S < 4; ++S) {
        const char* bufp;
        ITERTOP(bufp);
        f32x4 a00 = {0.f, 0.f, 0.f, 0.f}, a01 = a00, a10 = a00, a11 = a00;
        #pragma unroll
        for (int ss = 0; ss < 8; ++ss) {
            bf16x8 w0 = *(const bf16x8*)(bufp + (((ss) * 64 + lane) << 4));
            bf16x8 w1 = *(const bf16x8*)(bufp + (((8 + ss) * 64 + lane) << 4));
            a00 = MFMA(w0, xb[0][ss], a00);
            a01 = MFMA(w0, xb[1][ss], a01);
            a10 = MFMA(w1, xb[0][ss], a10);
            a11 = MFMA(w1, xb[1][ss], a11);
        }
        float4 b0 = *(const float4*)(gb + 4096 + q * 128 + 32 * S + 4 * lg4);
        float4 b1 = *(const float4*)(gb + 4096 + q * 128 + 32 * S + 16 + 4 * lg4);
        int4 u0, u1;
        u0.x = pk2(a00[0] + b0.x, a00[1] + b0.y);
        u0.y = pk2(a00[2] + b0.z, a00[3] + b0.w);
        u0.z = pk2(a10[0] + b1.x, a10[1] + b1.y);
        u0.w = pk2(a10[2] + b1.z, a10[3] + b1.w);
        xpf[0][S] = *(bf16x8*)&u0;
        u1.x = pk2(a01[0] + b0.x, a01[1] + b0.y);
        u1.y = pk2(a01[2] + b0.z, a01[3] + b0.w);
        u1.z = pk2(a11[0] + b1.x, a11[1] + b1.y);
        u1.w = pk2(a11[2] + b1.z, a11[3] + b1.w);
        xpf[1][S] = *(bf16x8*)&u1;
    }

    // ---- GEMM2: logits2 vs 1024 codes, A/B-pipelined epilogue ----
    const float* gq = gb + (q << 10);
    float lsum[2] = {0.f, 0.f};
    float bv[2]   = {0.f, 0.f};
    int   bi[2]   = {0, 0};
    f32x4 A[8], Bq[8];
    {
        const char* bufp;
        ITERTOP(bufp);
        mfma_chunk(bufp, lane, xpf, A);
    }
    #pragma unroll 1
    for (int t = 0; t < 7; ++t) {
        {
            const char* bufp;
            ITERTOP(bufp);
            mfma_chunk(bufp, lane, xpf, Bq);
            epi8<LEAN>(A, 2 * t, gq, lg4, lsum, bv);
        }
        {
            const char* bufp;
            ITERTOP(bufp);
            mfma_chunk(bufp, lane, xpf, A);
            epi8<LEAN>(Bq, 2 * t + 1, gq, lg4, lsum, bv);
        }
    }
    {
        const char* bufp;
        ITERTOP(bufp);
        mfma_chunk(bufp, lane, xpf, Bq);
        epi8<LEAN>(A, 14, gq, lg4, lsum, bv);
    }
    epi8<LEAN>(Bq, 15, gq, lg4, lsum, bv);

    // ---- pick = dot(xp_row, F[tgt_row]) - g[tgt] via MFMA diagonal ----
    float pickv[2];
    #pragma unroll
    for (int rf = 0; rf < 2; ++rf) {
        int t = tgt[rf];
        const char* fb = sq + ((4 + (t >> 6)) << 14)
                       + (((((t >> 4) & 3) << 8) + (lg4 << 4) + (t & 15)) << 4);
        bf16x8 f0 = *(const bf16x8*)(fb);
        bf16x8 f1 = *(const bf16x8*)(fb + 1024);
        bf16x8 f2 = *(const bf16x8*)(fb + 2048);
        bf16x8 f3 = *(const bf16x8*)(fb + 3072);
        f32x4 pa = {0.f, 0.f, 0.f, 0.f};
        pa = MFMA(f0, xpf[rf][0], pa);
        pa = MFMA(f1, xpf[rf][1], pa);
        pa = MFMA(f2, xpf[rf][2], pa);
        pa = MFMA(f3, xpf[rf][3], pa);
        int r = l15 & 3;
        float dv = (r == 0) ? pa[0] : ((r == 1) ? pa[1] : ((r == 2) ? pa[2] : pa[3]));
        float gt = gq[t];
        pickv[rf] = (lg4 == (l15 >> 2)) ? (dv - gt) : 0.f;
    }

    // ---- combine lane-groups ----
    #pragma unroll
    for (int rf = 0; rf < 2; ++rf) {
        float pk10 = 0.f;
        if (!LEAN) {
            unsigned pb = __float_as_uint(bv[rf]);
            unsigned code = ((pb & 63u) << 4) | (unsigned)(lg4 << 2) | ((pb >> 6) & 3u);
            pk10 = __uint_as_float((pb & 0xFFFFFC00u) | code);
        }
        #pragma unroll
        for (int off = 16; off <= 32; off <<= 1) {
            lsum[rf]  += __shfl_xor(lsum[rf], off);
            pickv[rf] += __shfl_xor(pickv[rf], off);
            if (!LEAN) pk10 = fmaxf(pk10, __shfl_xor(pk10, off));
        }
        if (!LEAN) bi[rf] = (int)(__float_as_uint(pk10) & 1023u);
        if (lane < 16) loss += LOG2(lsum[rf]) - pickv[rf];
    }

    // ---- residual update ----
    if (!LEAN) {
        const unsigned short* tq = tab + ((size_t)q << 18);
        #pragma unroll
        for (int rf = 0; rf < 2; ++rf) {
            const unsigned short* trow = tq + ((size_t)bi[rf] << 8) + (lg4 << 3);
            #pragma unroll
            for (int s = 0; s < 8; ++s) {
                int4 tv = *(const int4*)(trow + (s << 5));
                int4 xv = *(int4*)&xb[rf][s];
                int4 ov;
                ov.x = sub2(xv.x, tv.x); ov.y = sub2(xv.y, tv.y);
                ov.z = sub2(xv.z, tv.z); ov.w = sub2(xv.w, tv.w);
                *(int4*)&xb[rf][s] = ov;
            }
        }
    }
}

__global__ __launch_bounds__(256, 2) void rvq_k(
    const float* __restrict__ X,              // (B,256,4096) f32
    const unsigned short* __restrict__ stream,
    const float* __restrict__ gbias,          // [g 4096][bias 512] f32
    const unsigned short* __restrict__ tab,   // (3,1024,256) bf16
    const int* __restrict__ tlc,
    float* __restrict__ accp)
{
    __shared__ __align__(16) char LDSM[69632]; // 48K ring + 18K gb + 2K tgt

    const int tid  = threadIdx.x;
    const int lane = tid & 63;
    const int wv   = tid >> 6;
    const int l15  = lane & 15;
    const int lg4  = lane >> 4;
    const int row_base = blockIdx.x * 128 + wv * 32;

    // residual fragments: 32 rows x 256 d, bf16, loaded+transposed in-register
    bf16x8 xb[2][8];
    #pragma unroll
    for (int rf = 0; rf < 2; ++rf) {
        const int row = row_base + rf * 16 + l15;
        const float* xpr = X + ((size_t)(row >> 12) << 20) + (row & (T_ - 1));
        #pragma unroll
        for (int s = 0; s < 8; ++s) {
            float f[8];
            #pragma unroll
            for (int j = 0; j < 8; ++j)
                f[j] = xpr[(size_t)((s << 5) + (lg4 << 3) + j) << 12];
            int4 u;
            u.x = pk2(f[0], f[1]); u.y = pk2(f[2], f[3]);
            u.z = pk2(f[4], f[5]); u.w = pk2(f[6], f[7]);
            xb[rf][s] = *(bf16x8*)&u;
        }
    }

    // tlc prologue: each lane loads q=lg4's targets for its 2 rows -> LDS
    {
        int* tl = (int*)(LDSM + 67584);
        int q0 = lg4;
        int r0 = row_base + l15, r1 = row_base + 16 + l15;
        int t0 = tlc[(size_t)(r0 >> 12) * (NQn * T_) + q0 * T_ + (r0 & (T_ - 1))];
        int t1 = tlc[(size_t)(r1 >> 12) * (NQn * T_) + q0 * T_ + (r1 & (T_ - 1))];
        tl[(wv * 4 + q0) * 32 + l15] = t0;
        tl[(wv * 4 + q0) * 32 + 16 + l15] = t1;
    }
    __builtin_amdgcn_sched_barrier(0);

    // gb staging (18KB) + first two chunks
    const char* sbase = (const char*)stream;
    const char* send  = sbase + 80 * 16384;
    {
        const char* gs = (const char*)gbias;
        #pragma unroll
        for (int k = 0; k < 4; ++k)
            GLDS(gs + (((k * 4 + wv) * 64 + lane) << 4),
                 LDSM + 49152 + ((k * 4 + wv) << 10));
        if (wv < 2)
            GLDS(gs + 16384 + ((wv * 64 + lane) << 4),
                 LDSM + 49152 + 16384 + (wv << 10));
    }
    {
        const char* s0 = sbase + (wv << 12) + (lane << 4);
        char* d0 = LDSM + (wv << 12);
        GLDS(s0, d0); GLDS(s0 + 1024, d0 + 1024);
        GLDS(s0 + 2048, d0 + 2048); GLDS(s0 + 3072, d0 + 3072);
        const char* s1 = s0 + 16384;
        char* d1 = d0 + 16384;
        GLDS(s1, d1); GLDS(s1 + 1024, d1 + 1024);
        GLDS(s1 + 2048, d1 + 2048); GLDS(s1 + 3072, d1 + 3072);
    }
    const char* sp = sbase + 32768;
    int cslot = 0;
    __syncthreads();   // tgt LDS visible; staging counts consistent

    float loss = 0.f;
    const float* gb = (const float*)(LDSM + 49152);

    #pragma unroll 1
    for (int q = 0; q < 3; ++q)
        q_body<false>(q, LDSM, gb, sp, sbase, send, cslot,
                      wv, lane, l15, lg4, xb, tab,
                      sbase + (size_t)q * 327680, loss);
    q_body<true>(3, LDSM, gb, sp, sbase, send, cslot,
                 wv, lane, l15, lg4, xb, tab,
                 sbase + (size_t)3 * 327680, loss);

    asm volatile("s_waitcnt vmcnt(0)" ::: "memory");  // drain dummy tail stages
    #pragma unroll
    for (int off = 1; off < 64; off <<= 1) loss += __shfl_xor(loss, off);
    if (lane == 0) atomicAdd(accp, loss * 0.69314718056f);
}

// ---------------------------------------------------------------- launch
extern "C" void kernel_launch(void* const* d_in, const int* in_sizes, int n_in,
                              void* d_out, int out_size, void* d_ws, size_t ws_size,
                              hipStream_t stream_)
{
    (void)in_sizes; (void)n_in; (void)out_size; (void)ws_size;
    const float* dstart = (const float*)d_in[0];
    const int*   tlc    = (const int*)d_in[1];
    const float* Win    = (const float*)d_in[2];
    const float* bin    = (const float*)d_in[3];
    const float* Wout   = (const float*)d_in[4];
    const float* bout   = (const float*)d_in[5];
    const float* emb    = (const float*)d_in[6];

    char* ws = (char*)d_ws;
    size_t off = 0;
    unsigned short* strm = (unsigned short*)(ws + off); off += (size_t)80 * 16384;       // 1.25 MB
    unsigned short* tab  = (unsigned short*)(ws + off); off += (size_t)3 * K_ * D_ * 2;  // 1.5 MB
    float*          gbias= (float*)(ws + off);          off += (size_t)4608 * 4;         // 18 KB
    float*          accp = (float*)(ws + off);          off += 256;

    prep_all_k<<<577, 256, 0, stream_>>>(Win, bin, emb, Wout, bout,
                                         strm, tab, gbias, accp);
    rvq_k<<<512, 256, 0, stream_>>>(dstart, strm, gbias, tab, tlc, accp);
    final_k<<<1, 1, 0, stream_>>>(accp, (float*)d_out);
}